// Round 2
// baseline (288.839 us; speedup 1.0000x reference)
//
#include <hip/hip_runtime.h>
#include <stdint.h>

#define HH 512
#define WW 512
#define NB 8
#define RAD 10
#define NPASS 51
#define WPR 16                 // u32 words per row
#define IMG_WORDS (HH*WPR)     // 8192 words per image
#define PAD 18                 // padded LDS row stride (bank-conflict-free)

// ---- Kernel 1: det bits (x1>x0) + per-image argmax of monotone(x1-x0) ------
__global__ __launch_bounds__(256) void k_det(const float* __restrict__ in,
                                             uint32_t* __restrict__ det,
                                             unsigned long long* __restrict__ keys) {
    int tid  = blockIdx.x * 256 + threadIdx.x;
    int lane = threadIdx.x & 63;
    int wave = tid >> 6;
    long long base = (long long)wave * 256;     // 4 rounds x 64 pixels
    int img = (int)(base >> 18);                // 262144 px per image
    unsigned long long best = 0;
    const float2* in2 = (const float2*)in;
    #pragma unroll
    for (int j = 0; j < 4; ++j) {
        long long p = base + j * 64 + lane;
        float2 v = in2[p];
        // round(softmax_1(v)) == 1  <=>  v.y > v.x   (exact; no expf needed)
        float d = v.y - v.x;
        int pred = (d > 0.0f);
        unsigned long long bits = __ballot(pred);
        if (lane == 0) ((unsigned long long*)det)[wave * 4 + j] = bits;
        // argmax of softmax_1 == argmax of d (sigmoid strictly monotone).
        // Map float d -> order-preserving u32, then (mono<<32)|~idx, take max
        // => max value, first index on ties (matches jnp.argmax).
        uint32_t du = __float_as_uint(d);
        uint32_t mono = (du & 0x80000000u) ? ~du : (du | 0x80000000u);
        uint32_t pix = (uint32_t)(p & (HH * WW - 1));
        unsigned long long key = ((unsigned long long)mono << 32)
                               | (unsigned long long)(0xFFFFFFFFu - pix);
        best = key > best ? key : best;
    }
    #pragma unroll
    for (int s = 32; s > 0; s >>= 1) {
        unsigned long long o = __shfl_xor(best, s);
        best = o > best ? o : best;
    }
    if (lane == 0) atomicMax(&keys[img], best);
}

// ---- Kernel 2: geodesic dilation (binary, bit-packed), one block/image -----
__global__ __launch_bounds__(1024) void k_grow(const uint32_t* __restrict__ det,
                                               const unsigned long long* __restrict__ keys,
                                               uint32_t* __restrict__ outmask) {
    __shared__ uint32_t cur[HH * PAD];   // 36 KB
    __shared__ uint32_t hb [HH * PAD];   // 36 KB
    __shared__ uint32_t flags[2];
    int b  = blockIdx.x;
    int t  = threadIdx.x;
    int w  = t & 15;                     // word-in-row
    int r0 = (t >> 4) << 3;              // first of 8 rows this thread owns
    uint32_t dreg[8], curreg[8];
    const uint32_t* db = det + b * IMG_WORDS;
    #pragma unroll
    for (int k = 0; k < 8; ++k) dreg[k] = db[(r0 + k) * WPR + w];

    unsigned long long key = keys[b];
    uint32_t pix = 0xFFFFFFFFu - (uint32_t)key;
    int sr = pix >> 9, sc = pix & 511;
    #pragma unroll
    for (int k = 0; k < 8; ++k) {        // seed (every thread writes own words)
        uint32_t v = (sr == r0 + k && (sc >> 5) == w) ? (1u << (sc & 31)) : 0u;
        curreg[k] = v;
        cur[(r0 + k) * PAD + w] = v;
    }
    if (t == 0) { flags[0] = 0; flags[1] = 0; }
    __syncthreads();

    for (int it = 0; it < NPASS; ++it) {
        // horizontal dilation radius 10 (96-bit window via two u64)
        #pragma unroll
        for (int k = 0; k < 8; ++k) {
            int r = r0 + k;
            uint32_t a  = (w > 0)  ? cur[r * PAD + w - 1] : 0u;
            uint32_t c  = (w < 15) ? cur[r * PAD + w + 1] : 0u;
            uint32_t bb = curreg[k];
            unsigned long long L  = ((unsigned long long)bb << 32) | a;
            unsigned long long Hh = ((unsigned long long)c  << 32) | bb;
            uint32_t o = bb;
            #pragma unroll
            for (int s = 1; s <= RAD; ++s)
                o |= (uint32_t)(L >> (32 - s)) | (uint32_t)(Hh >> s);
            hb[r * PAD + w] = o;
        }
        __syncthreads();
        if (t == 0) flags[(it + 1) & 1] = 0;

        // vertical dilation radius 10 (21-row OR via log tree) + AND det
        uint32_t x[28];
        #pragma unroll
        for (int k = 0; k < 28; ++k) {
            int r = r0 - RAD + k;
            x[k] = (r >= 0 && r < HH) ? hb[r * PAD + w] : 0u;
        }
        uint32_t or2[26];
        #pragma unroll
        for (int i = 0; i < 26; ++i) or2[i] = x[i] | x[i + 1];
        uint32_t or4[24];
        #pragma unroll
        for (int i = 0; i < 24; ++i) or4[i] = or2[i] | or2[i + 2];
        uint32_t or8[16];
        #pragma unroll
        for (int i = 0; i < 16; ++i) or8[i] = or4[i] | or4[i + 4];
        uint32_t diff = 0;
        #pragma unroll
        for (int k = 0; k < 8; ++k) {
            uint32_t o21 = (or8[k] | or8[k + 8]) | or4[k + 16] | x[k + 20];
            uint32_t nv  = dreg[k] & o21;
            diff |= nv ^ curreg[k];
            curreg[k] = nv;
            cur[(r0 + k) * PAD + w] = nv;
        }
        if (diff) flags[it & 1] = 1;
        __syncthreads();
        if (!flags[it & 1]) break;       // fixed point -> identical to full 51
    }
    #pragma unroll
    for (int k = 0; k < 8; ++k)
        outmask[b * IMG_WORDS + (r0 + k) * WPR + w] = curreg[k];
}

// ---- Kernel 3: bits -> float, tiled 8x -------------------------------------
__global__ __launch_bounds__(256) void k_expand(const uint32_t* __restrict__ mask,
                                                float* __restrict__ out) {
    int t   = blockIdx.x * 256 + threadIdx.x;   // 4,194,304 threads, float4 each
    int img = t >> 16;                          // 65536 float4 per image
    int pix = (t & 65535) << 2;
    uint32_t wv = mask[(img & 7) * IMG_WORDS + (pix >> 5)];
    int sh = pix & 31;
    float4 o;
    o.x = (wv >> (sh + 0)) & 1 ? 1.0f : 0.0f;
    o.y = (wv >> (sh + 1)) & 1 ? 1.0f : 0.0f;
    o.z = (wv >> (sh + 2)) & 1 ? 1.0f : 0.0f;
    o.w = (wv >> (sh + 3)) & 1 ? 1.0f : 0.0f;
    ((float4*)out)[t] = o;
}

extern "C" void kernel_launch(void* const* d_in, const int* in_sizes, int n_in,
                              void* d_out, int out_size, void* d_ws, size_t ws_size,
                              hipStream_t stream) {
    const float* in = (const float*)d_in[0];
    float* out = (float*)d_out;
    unsigned long long* keys = (unsigned long long*)d_ws;
    uint32_t* det = (uint32_t*)((char*)d_ws + 256);
    uint32_t* fin = (uint32_t*)((char*)d_ws + 256 + NB * IMG_WORDS * 4);

    hipMemsetAsync(d_ws, 0, 256, stream);                  // zero argmax keys
    k_det   <<<2048,  256, 0, stream>>>(in, det, keys);
    k_grow  <<<NB,   1024, 0, stream>>>(det, keys, fin);
    k_expand<<<16384, 256, 0, stream>>>(fin, out);
}

// Round 3
// 133.360 us; speedup vs baseline: 2.1659x; 2.1659x over previous
//
#include <hip/hip_runtime.h>
#include <stdint.h>

#define HH 512
#define WW 512
#define NB 8
#define RAD 10
#define NPASS 51
#define WPR 16                 // u32 words per row
#define IMG_WORDS (HH*WPR)     // 8192 words per image
#define PAD 18                 // padded LDS row stride (2-way banks = free)
#define GROWS (HH + 2*RAD)     // hb rows incl. 10 zero guard rows each side

// ---- Kernel 1: det bits (x1>x0) + per-image argmax, block-reduced ----------
__global__ __launch_bounds__(256) void k_det(const float* __restrict__ in,
                                             uint32_t* __restrict__ det,
                                             unsigned long long* __restrict__ keys) {
    __shared__ unsigned long long red[4];
    int tid  = blockIdx.x * 256 + threadIdx.x;
    int lane = threadIdx.x & 63;
    int wv   = threadIdx.x >> 6;
    int wave = tid >> 6;
    long long base = (long long)wave * 256;     // 4 rounds x 64 pixels
    int img = (int)(base >> 18);                // 262144 px per image
    unsigned long long best = 0;
    const float2* in2 = (const float2*)in;
    #pragma unroll
    for (int j = 0; j < 4; ++j) {
        long long p = base + j * 64 + lane;
        float2 v = in2[p];
        // round(softmax_1(v)) == 1  <=>  v.y > v.x   (exact; no expf needed)
        float d = v.y - v.x;
        int pred = (d > 0.0f);
        unsigned long long bits = __ballot(pred);
        if (lane == 0) ((unsigned long long*)det)[wave * 4 + j] = bits;
        // argmax of softmax_1 == argmax of d (sigmoid strictly monotone).
        uint32_t du = __float_as_uint(d);
        uint32_t mono = (du & 0x80000000u) ? ~du : (du | 0x80000000u);
        uint32_t pix = (uint32_t)(p & (HH * WW - 1));
        unsigned long long key = ((unsigned long long)mono << 32)
                               | (unsigned long long)(0xFFFFFFFFu - pix);
        best = key > best ? key : best;
    }
    #pragma unroll
    for (int s = 32; s > 0; s >>= 1) {
        unsigned long long o = __shfl_xor(best, s);
        best = o > best ? o : best;
    }
    if (lane == 0) red[wv] = best;
    __syncthreads();
    if (threadIdx.x == 0) {
        unsigned long long b0 = red[0], b1 = red[1], b2 = red[2], b3 = red[3];
        b0 = b0 > b1 ? b0 : b1;
        b2 = b2 > b3 ? b2 : b3;
        b0 = b0 > b2 ? b0 : b2;
        atomicMax(&keys[img], b0);      // 2048 atomics total, 256 per image
    }
}

// ---- Kernel 2: geodesic dilation (binary, bit-packed), one block/image -----
__global__ __launch_bounds__(1024) void k_grow(const uint32_t* __restrict__ det,
                                               const unsigned long long* __restrict__ keys,
                                               uint32_t* __restrict__ outmask) {
    __shared__ uint32_t hb[GROWS * PAD];   // ~37.4 KB, rows offset by +RAD
    __shared__ uint32_t flags[2];
    int b  = blockIdx.x;
    int t  = threadIdx.x;
    int w  = t & 15;                     // word-in-row == lane&15 (DPP row!)
    int r0 = (t >> 4) << 3;              // first of 8 rows this thread owns
    uint32_t dreg[8], curreg[8];
    const uint32_t* db = det + b * IMG_WORDS;
    #pragma unroll
    for (int k = 0; k < 8; ++k) dreg[k] = db[(r0 + k) * WPR + w];

    unsigned long long key = keys[b];
    uint32_t pix = 0xFFFFFFFFu - (uint32_t)key;
    int sr = pix >> 9, sc = pix & 511;
    #pragma unroll
    for (int k = 0; k < 8; ++k)          // sparse seed, registers only
        curreg[k] = (sr == r0 + k && (sc >> 5) == w) ? (1u << (sc & 31)) : 0u;

    // zero the 2*RAD guard rows once (never written again)
    if (t < 2 * RAD * WPR) {
        int gr = t >> 4;
        hb[((gr < RAD ? gr : gr + HH) ) * PAD + (t & 15)] = 0;
    }
    if (t == 0) { flags[0] = 0; flags[1] = 0; }
    __syncthreads();

    for (int it = 0; it < NPASS; ++it) {
        // ---- horizontal dilation radius 10: DPP neighbors + u64 log-doubling
        #pragma unroll
        for (int k = 0; k < 8; ++k) {
            uint32_t bb = curreg[k];
            uint32_t a = (uint32_t)__builtin_amdgcn_update_dpp(
                0, (int)bb, 0x111, 0xF, 0xF, true);   // lane w-1 (0 at w==0)
            uint32_t c = (uint32_t)__builtin_amdgcn_update_dpp(
                0, (int)bb, 0x101, 0xF, 0xF, true);   // lane w+1 (0 at w==15)
            unsigned long long W = (unsigned long long)(a >> 22)
                                 | ((unsigned long long)bb << 10)
                                 | ((unsigned long long)c << 42);
            unsigned long long D = W | (W >> 1);      // offsets [0,1]
            D |= D >> 2;                              // [0,3]
            D |= D >> 4;                              // [0,7]
            unsigned long long D7 = D;
            D |= D >> 8;                              // [0,15]
            D |= D7 >> 13;                            // | [13,20] = [0,20]
            hb[(r0 + k + RAD) * PAD + w] = (uint32_t)D;
        }
        __syncthreads();
        if (t == 0) flags[(it + 1) & 1] = 0;

        // ---- vertical 21-row OR via suffix/prefix + AND det ----
        uint32_t x[28];
        #pragma unroll
        for (int j = 0; j < 28; ++j) x[j] = hb[(r0 + j) * PAD + w];
        uint32_t s[21];
        s[20] = x[20];
        #pragma unroll
        for (int i = 19; i >= 0; --i) s[i] = x[i] | s[i + 1];
        uint32_t p[28];
        p[21] = x[21];
        #pragma unroll
        for (int i = 22; i < 28; ++i) p[i] = x[i] | p[i - 1];
        uint32_t diff = 0;
        {
            uint32_t nv = dreg[0] & s[0];
            diff |= nv ^ curreg[0];
            curreg[0] = nv;
        }
        #pragma unroll
        for (int k = 1; k < 8; ++k) {
            uint32_t nv = dreg[k] & (s[k] | p[k + 20]);
            diff |= nv ^ curreg[k];
            curreg[k] = nv;
        }
        if (diff) flags[it & 1] = 1;
        __syncthreads();
        if (!flags[it & 1]) break;       // fixed point -> identical to full 51
    }
    #pragma unroll
    for (int k = 0; k < 8; ++k)
        outmask[b * IMG_WORDS + (r0 + k) * WPR + w] = curreg[k];
}

// ---- Kernel 3: bits -> float, tiled 8x -------------------------------------
__global__ __launch_bounds__(256) void k_expand(const uint32_t* __restrict__ mask,
                                                float* __restrict__ out) {
    int t   = blockIdx.x * 256 + threadIdx.x;   // 4,194,304 threads, float4 each
    int img = t >> 16;                          // 65536 float4 per image
    int pix = (t & 65535) << 2;
    uint32_t wv = mask[(img & 7) * IMG_WORDS + (pix >> 5)];
    int sh = pix & 31;
    float4 o;
    o.x = (wv >> (sh + 0)) & 1 ? 1.0f : 0.0f;
    o.y = (wv >> (sh + 1)) & 1 ? 1.0f : 0.0f;
    o.z = (wv >> (sh + 2)) & 1 ? 1.0f : 0.0f;
    o.w = (wv >> (sh + 3)) & 1 ? 1.0f : 0.0f;
    ((float4*)out)[t] = o;
}

extern "C" void kernel_launch(void* const* d_in, const int* in_sizes, int n_in,
                              void* d_out, int out_size, void* d_ws, size_t ws_size,
                              hipStream_t stream) {
    const float* in = (const float*)d_in[0];
    float* out = (float*)d_out;
    unsigned long long* keys = (unsigned long long*)d_ws;
    uint32_t* det = (uint32_t*)((char*)d_ws + 256);
    uint32_t* fin = (uint32_t*)((char*)d_ws + 256 + NB * IMG_WORDS * 4);

    hipMemsetAsync(d_ws, 0, 256, stream);                  // zero argmax keys
    k_det   <<<2048,  256, 0, stream>>>(in, det, keys);
    k_grow  <<<NB,   1024, 0, stream>>>(det, keys, fin);
    k_expand<<<16384, 256, 0, stream>>>(fin, out);
}

// Round 4
// 121.651 us; speedup vs baseline: 2.3743x; 1.0962x over previous
//
#include <hip/hip_runtime.h>
#include <stdint.h>

#define HH 512
#define WW 512
#define NB 8
#define RAD 10
#define NPASS 51
#define WPR 16                 // u32 words per row
#define IMG_WORDS (HH*WPR)     // 8192 words per image
#define STRIDE 540             // words per LDS column: 12 guard + 512 + 16 guard
#define GLO 12                 // low guard rows (16B-alignment friendly)

// ---- Kernel 1: det bits (x1>x0) + per-BLOCK argmax key (no atomics) --------
__global__ __launch_bounds__(256) void k_det(const float* __restrict__ in,
                                             uint32_t* __restrict__ det,
                                             unsigned long long* __restrict__ keys) {
    __shared__ unsigned long long red[4];
    int tid  = blockIdx.x * 256 + threadIdx.x;
    int lane = threadIdx.x & 63;
    int wv   = threadIdx.x >> 6;
    int wave = tid >> 6;
    long long base = (long long)wave * 256;     // 4 rounds x 64 pixels
    unsigned long long best = 0;
    const float2* in2 = (const float2*)in;
    #pragma unroll
    for (int j = 0; j < 4; ++j) {
        long long p = base + j * 64 + lane;
        float2 v = in2[p];
        // round(softmax_1(v)) == 1  <=>  v.y > v.x   (exact; no expf needed)
        float d = v.y - v.x;
        int pred = (d > 0.0f);
        unsigned long long bits = __ballot(pred);
        if (lane == 0) ((unsigned long long*)det)[wave * 4 + j] = bits;
        // argmax of softmax_1 == argmax of d (sigmoid strictly monotone).
        uint32_t du = __float_as_uint(d);
        uint32_t mono = (du & 0x80000000u) ? ~du : (du | 0x80000000u);
        uint32_t pix = (uint32_t)(p & (HH * WW - 1));
        unsigned long long key = ((unsigned long long)mono << 32)
                               | (unsigned long long)(0xFFFFFFFFu - pix);
        best = key > best ? key : best;
    }
    #pragma unroll
    for (int s = 32; s > 0; s >>= 1) {
        unsigned long long o = __shfl_xor(best, s);
        best = o > best ? o : best;
    }
    if (lane == 0) red[wv] = best;
    __syncthreads();
    if (threadIdx.x == 0) {
        unsigned long long b0 = red[0], b1 = red[1], b2 = red[2], b3 = red[3];
        b0 = b0 > b1 ? b0 : b1;
        b2 = b2 > b3 ? b2 : b3;
        keys[blockIdx.x] = b0 > b2 ? b0 : b2;   // plain store, no atomics
    }
}

// ---- Kernel 2: geodesic dilation (bit-packed), transposed LDS, b128 I/O ----
__global__ __launch_bounds__(1024) void k_grow(const uint32_t* __restrict__ det,
                                               const unsigned long long* __restrict__ keys,
                                               uint32_t* __restrict__ outmask) {
    __shared__ __align__(16) uint32_t hb[WPR * STRIDE];  // 34.6 KB, column-major
    __shared__ uint32_t flags[2];
    __shared__ unsigned long long redk[4];
    int b    = blockIdx.x;
    int t    = threadIdx.x;
    int lane = t & 63;
    int wvid = t >> 6;
    int w    = t & 15;                   // word-in-row == lane&15 (DPP row!)
    int r0   = (t >> 4) << 3;            // first of 8 rows this thread owns
    uint32_t dreg[8];
    const uint32_t* db = det + b * IMG_WORDS;
    #pragma unroll
    for (int k = 0; k < 8; ++k) dreg[k] = db[(r0 + k) * WPR + w];

    // reduce this image's 256 block keys -> single argmax key
    unsigned long long kk = (t < 256) ? keys[b * 256 + t] : 0ull;
    #pragma unroll
    for (int s = 32; s > 0; s >>= 1) {
        unsigned long long o = __shfl_xor(kk, s);
        kk = o > kk ? o : kk;
    }
    if (lane == 0 && wvid < 4) redk[wvid] = kk;

    // zero-init hb (guards must stay zero; interior correct-by-induction)
    for (int i = t; i < WPR * STRIDE; i += 1024) hb[i] = 0;
    if (t == 0) { flags[0] = 0; flags[1] = 0; }
    __syncthreads();

    unsigned long long key = redk[0];
    key = redk[1] > key ? redk[1] : key;
    key = redk[2] > key ? redk[2] : key;
    key = redk[3] > key ? redk[3] : key;
    uint32_t pix = 0xFFFFFFFFu - (uint32_t)key;
    int sr = pix >> 9, sc = pix & 511;
    uint32_t curreg[8];
    #pragma unroll
    for (int k = 0; k < 8; ++k)          // sparse seed, registers only
        curreg[k] = (sr == r0 + k && (sc >> 5) == w) ? (1u << (sc & 31)) : 0u;

    uint32_t* colv = &hb[w * STRIDE];    // this thread's word-column

    for (int it = 0; it < NPASS; ++it) {
        // ---- horizontal dilation radius 10: DPP neighbors + u64 log-doubling
        uint32_t Dv[8];
        #pragma unroll
        for (int k = 0; k < 8; ++k) {
            uint32_t bb = curreg[k];
            uint32_t a = (uint32_t)__builtin_amdgcn_update_dpp(
                0, (int)bb, 0x111, 0xF, 0xF, true);   // word w-1 (0 at w==0)
            uint32_t c = (uint32_t)__builtin_amdgcn_update_dpp(
                0, (int)bb, 0x101, 0xF, 0xF, true);   // word w+1 (0 at w==15)
            unsigned long long W = (unsigned long long)(a >> 22)
                                 | ((unsigned long long)bb << 10)
                                 | ((unsigned long long)c << 42);
            unsigned long long D = W | (W >> 1);      // offsets [0,1]
            D |= D >> 2;                              // [0,3]
            D |= D >> 4;                              // [0,7]
            unsigned long long D7 = D;
            D |= D >> 8;                              // [0,15]
            D |= D7 >> 13;                            // | [13,20] = [0,20]
            Dv[k] = (uint32_t)D;
        }
        // store 8 contiguous rows of column w: 2x ds_write_b128
        *(uint4*)&colv[r0 + GLO]     = make_uint4(Dv[0], Dv[1], Dv[2], Dv[3]);
        *(uint4*)&colv[r0 + GLO + 4] = make_uint4(Dv[4], Dv[5], Dv[6], Dv[7]);
        __syncthreads();
        if (t == 0) flags[(it + 1) & 1] = 0;

        // ---- vertical 21-row OR: 6x ds_read_b128 + own rows from registers
        uint32_t x[28];                  // x[j] = H-out row (r0-10+j), col w
        {
            uint4 A0 = *(const uint4*)&colv[r0];          // rows r0-12..r0-9
            uint4 A1 = *(const uint4*)&colv[r0 + 4];      // rows r0-8..r0-5
            uint4 A2 = *(const uint4*)&colv[r0 + 8];      // rows r0-4..r0-1
            uint4 B0 = *(const uint4*)&colv[r0 + 20];     // rows r0+8..r0+11
            uint4 B1 = *(const uint4*)&colv[r0 + 24];     // rows r0+12..r0+15
            uint4 B2 = *(const uint4*)&colv[r0 + 28];     // rows r0+16..r0+19
            x[0] = A0.z;  x[1] = A0.w;
            x[2] = A1.x;  x[3] = A1.y;  x[4] = A1.z;  x[5] = A1.w;
            x[6] = A2.x;  x[7] = A2.y;  x[8] = A2.z;  x[9] = A2.w;
            #pragma unroll
            for (int k = 0; k < 8; ++k) x[10 + k] = Dv[k];
            x[18] = B0.x; x[19] = B0.y; x[20] = B0.z; x[21] = B0.w;
            x[22] = B1.x; x[23] = B1.y; x[24] = B1.z; x[25] = B1.w;
            x[26] = B2.x; x[27] = B2.y;
        }
        uint32_t s[21];
        s[20] = x[20];
        #pragma unroll
        for (int i = 19; i >= 0; --i) s[i] = x[i] | s[i + 1];
        uint32_t p[28];
        p[21] = x[21];
        #pragma unroll
        for (int i = 22; i < 28; ++i) p[i] = x[i] | p[i - 1];
        uint32_t diff = 0;
        {
            uint32_t nv = dreg[0] & s[0];
            diff |= nv ^ curreg[0];
            curreg[0] = nv;
        }
        #pragma unroll
        for (int k = 1; k < 8; ++k) {
            uint32_t nv = dreg[k] & (s[k] | p[k + 20]);
            diff |= nv ^ curreg[k];
            curreg[k] = nv;
        }
        if (diff) flags[it & 1] = 1;
        __syncthreads();
        if (!flags[it & 1]) break;       // fixed point -> identical to full 51
    }
    #pragma unroll
    for (int k = 0; k < 8; ++k)
        outmask[b * IMG_WORDS + (r0 + k) * WPR + w] = curreg[k];
}

// ---- Kernel 3: bits -> float, tiled 8x -------------------------------------
__global__ __launch_bounds__(256) void k_expand(const uint32_t* __restrict__ mask,
                                                float* __restrict__ out) {
    int t   = blockIdx.x * 256 + threadIdx.x;   // 4,194,304 threads, float4 each
    int img = t >> 16;                          // 65536 float4 per image
    int pix = (t & 65535) << 2;
    uint32_t wv = mask[(img & 7) * IMG_WORDS + (pix >> 5)];
    int sh = pix & 31;
    float4 o;
    o.x = (wv >> (sh + 0)) & 1 ? 1.0f : 0.0f;
    o.y = (wv >> (sh + 1)) & 1 ? 1.0f : 0.0f;
    o.z = (wv >> (sh + 2)) & 1 ? 1.0f : 0.0f;
    o.w = (wv >> (sh + 3)) & 1 ? 1.0f : 0.0f;
    ((float4*)out)[t] = o;
}

extern "C" void kernel_launch(void* const* d_in, const int* in_sizes, int n_in,
                              void* d_out, int out_size, void* d_ws, size_t ws_size,
                              hipStream_t stream) {
    const float* in = (const float*)d_in[0];
    float* out = (float*)d_out;
    unsigned long long* keys = (unsigned long long*)d_ws;          // 2048 x u64
    uint32_t* det = (uint32_t*)((char*)d_ws + 2048 * 8);
    uint32_t* fin = (uint32_t*)((char*)d_ws + 2048 * 8 + NB * IMG_WORDS * 4);

    k_det   <<<2048,  256, 0, stream>>>(in, det, keys);
    k_grow  <<<NB,   1024, 0, stream>>>(det, keys, fin);
    k_expand<<<16384, 256, 0, stream>>>(fin, out);
}

// Round 5
// 110.920 us; speedup vs baseline: 2.6040x; 1.0967x over previous
//
#include <hip/hip_runtime.h>
#include <stdint.h>

#define HH 512
#define WW 512
#define NB 8
#define RAD 10
#define NPASS 51
#define WPR 16                 // u32 words per row
#define IMG_WORDS (HH*WPR)     // 8192 words per image
#define STRIDE 540             // words per LDS column: 12 low guard + 512 + 16 high guard
#define GLO 12                 // low guard rows (keeps b128 writes 16B-aligned)

// ---- Kernel 1: det bits (x1>x0) + per-BLOCK argmax key (no atomics) --------
__global__ __launch_bounds__(256) void k_det(const float* __restrict__ in,
                                             uint32_t* __restrict__ det,
                                             unsigned long long* __restrict__ keys) {
    __shared__ unsigned long long red[4];
    int tid  = blockIdx.x * 256 + threadIdx.x;
    int lane = threadIdx.x & 63;
    int wv   = threadIdx.x >> 6;
    int wave = tid >> 6;
    long long base = (long long)wave * 256;     // 4 rounds x 64 pixels
    unsigned long long best = 0;
    const float2* in2 = (const float2*)in;
    #pragma unroll
    for (int j = 0; j < 4; ++j) {
        long long p = base + j * 64 + lane;
        float2 v = in2[p];
        // round(softmax_1(v)) == 1  <=>  v.y > v.x   (exact; no expf needed)
        float d = v.y - v.x;
        int pred = (d > 0.0f);
        unsigned long long bits = __ballot(pred);
        if (lane == 0) ((unsigned long long*)det)[wave * 4 + j] = bits;
        // argmax of softmax_1 == argmax of d (sigmoid strictly monotone).
        uint32_t du = __float_as_uint(d);
        uint32_t mono = (du & 0x80000000u) ? ~du : (du | 0x80000000u);
        uint32_t pix = (uint32_t)(p & (HH * WW - 1));
        unsigned long long key = ((unsigned long long)mono << 32)
                               | (unsigned long long)(0xFFFFFFFFu - pix);
        best = key > best ? key : best;
    }
    #pragma unroll
    for (int s = 32; s > 0; s >>= 1) {
        unsigned long long o = __shfl_xor(best, s);
        best = o > best ? o : best;
    }
    if (lane == 0) red[wv] = best;
    __syncthreads();
    if (threadIdx.x == 0) {
        unsigned long long b0 = red[0], b1 = red[1], b2 = red[2], b3 = red[3];
        b0 = b0 > b1 ? b0 : b1;
        b2 = b2 > b3 ? b2 : b3;
        keys[blockIdx.x] = b0 > b2 ? b0 : b2;   // plain store, no atomics
    }
}

// ---- Kernel 2: geodesic dilation, double-buffered LDS, 1 barrier/iter ------
__global__ __launch_bounds__(1024) void k_grow(const uint32_t* __restrict__ det,
                                               const unsigned long long* __restrict__ keys,
                                               uint32_t* __restrict__ outmask) {
    __shared__ __align__(16) uint32_t hb[2][WPR * STRIDE];  // 69 KB, col-major
    __shared__ uint32_t flag[NPASS];
    __shared__ unsigned long long redk[4];
    int b    = blockIdx.x;
    int t    = threadIdx.x;
    int lane = t & 63;
    int wvid = t >> 6;
    int w    = t & 15;                   // word-in-row == lane&15 (DPP row!)
    int r0   = (t >> 4) << 3;            // first of 8 rows this thread owns
    uint32_t dreg[8];
    const uint32_t* db = det + b * IMG_WORDS;
    #pragma unroll
    for (int k = 0; k < 8; ++k) dreg[k] = db[(r0 + k) * WPR + w];

    // reduce this image's 256 block keys -> single argmax key
    unsigned long long kk = (t < 256) ? keys[b * 256 + t] : 0ull;
    #pragma unroll
    for (int s = 32; s > 0; s >>= 1) {
        unsigned long long o = __shfl_xor(kk, s);
        kk = o > kk ? o : kk;
    }
    if (lane == 0 && wvid < 4) redk[wvid] = kk;

    // zero-init both hb buffers (guards must stay zero) + flags
    for (int i = t; i < 2 * WPR * STRIDE; i += 1024) hb[0][i] = 0;
    if (t < NPASS) flag[t] = 0;
    __syncthreads();

    unsigned long long key = redk[0];
    key = redk[1] > key ? redk[1] : key;
    key = redk[2] > key ? redk[2] : key;
    key = redk[3] > key ? redk[3] : key;
    uint32_t pix = 0xFFFFFFFFu - (uint32_t)key;
    int sr = pix >> 9, sc = pix & 511;
    uint32_t curreg[8];
    #pragma unroll
    for (int k = 0; k < 8; ++k)          // sparse seed, registers only
        curreg[k] = (sr == r0 + k && (sc >> 5) == w) ? (1u << (sc & 31)) : 0u;

    for (int it = 0; it < NPASS; ++it) {
        uint32_t* colv = &hb[it & 1][w * STRIDE];
        // ---- horizontal dilation radius 10: DPP neighbors + u64 log-doubling
        uint32_t Dv[8];
        #pragma unroll
        for (int k = 0; k < 8; ++k) {
            uint32_t bb = curreg[k];
            uint32_t a = (uint32_t)__builtin_amdgcn_update_dpp(
                0, (int)bb, 0x111, 0xF, 0xF, true);   // word w-1 (0 at w==0)
            uint32_t c = (uint32_t)__builtin_amdgcn_update_dpp(
                0, (int)bb, 0x101, 0xF, 0xF, true);   // word w+1 (0 at w==15)
            unsigned long long W = (unsigned long long)(a >> 22)
                                 | ((unsigned long long)bb << 10)
                                 | ((unsigned long long)c << 42);
            unsigned long long D = W | (W >> 1);      // offsets [0,1]
            D |= D >> 2;                              // [0,3]
            D |= D >> 4;                              // [0,7]
            unsigned long long D7 = D;
            D |= D >> 8;                              // [0,15]
            D |= D7 >> 13;                            // | [13,20] = [0,20]
            Dv[k] = (uint32_t)D;
        }
        // store 8 contiguous rows of column w: 2x ds_write_b128
        *(uint4*)&colv[r0 + GLO]     = make_uint4(Dv[0], Dv[1], Dv[2], Dv[3]);
        *(uint4*)&colv[r0 + GLO + 4] = make_uint4(Dv[4], Dv[5], Dv[6], Dv[7]);
        __syncthreads();                 // the ONLY barrier per iteration

        // early exit: fixed point detected at iter it-1 -> curreg already final
        if (it > 0 && flag[it - 1] == 0) break;

        // ---- vertical 21-row OR: 10x ds_read_b64 halo + own rows from regs
        uint32_t x[28];                  // x[j] = H-out of row (r0-10+j)
        #pragma unroll
        for (int k = 0; k < 5; ++k) {    // rows r0-10 .. r0-1  (idx even: ok)
            uint2 u = *(const uint2*)&colv[r0 + GLO - 10 + 2 * k];
            x[2 * k]     = u.x;
            x[2 * k + 1] = u.y;
        }
        #pragma unroll
        for (int k = 0; k < 8; ++k) x[10 + k] = Dv[k];
        #pragma unroll
        for (int k = 0; k < 5; ++k) {    // rows r0+8 .. r0+17
            uint2 u = *(const uint2*)&colv[r0 + GLO + 8 + 2 * k];
            x[18 + 2 * k] = u.x;
            x[19 + 2 * k] = u.y;
        }
        uint32_t s[21];
        s[20] = x[20];
        #pragma unroll
        for (int i = 19; i >= 0; --i) s[i] = x[i] | s[i + 1];
        uint32_t p[28];
        p[21] = x[21];
        #pragma unroll
        for (int i = 22; i < 28; ++i) p[i] = x[i] | p[i - 1];
        uint32_t diff = 0;
        {
            uint32_t nv = dreg[0] & s[0];
            diff |= nv ^ curreg[0];
            curreg[0] = nv;
        }
        #pragma unroll
        for (int k = 1; k < 8; ++k) {
            uint32_t nv = dreg[k] & (s[k] | p[k + 20]);
            diff |= nv ^ curreg[k];
            curreg[k] = nv;
        }
        if (diff) flag[it] = 1;          // read only after NEXT barrier
    }
    #pragma unroll
    for (int k = 0; k < 8; ++k)
        outmask[b * IMG_WORDS + (r0 + k) * WPR + w] = curreg[k];
}

// ---- Kernel 3: bits -> float, tiled 8x -------------------------------------
__global__ __launch_bounds__(256) void k_expand(const uint32_t* __restrict__ mask,
                                                float* __restrict__ out) {
    int t   = blockIdx.x * 256 + threadIdx.x;   // 4,194,304 threads, float4 each
    int img = t >> 16;                          // 65536 float4 per image
    int pix = (t & 65535) << 2;
    uint32_t wv = mask[(img & 7) * IMG_WORDS + (pix >> 5)];
    int sh = pix & 31;
    float4 o;
    o.x = (wv >> (sh + 0)) & 1 ? 1.0f : 0.0f;
    o.y = (wv >> (sh + 1)) & 1 ? 1.0f : 0.0f;
    o.z = (wv >> (sh + 2)) & 1 ? 1.0f : 0.0f;
    o.w = (wv >> (sh + 3)) & 1 ? 1.0f : 0.0f;
    ((float4*)out)[t] = o;
}

extern "C" void kernel_launch(void* const* d_in, const int* in_sizes, int n_in,
                              void* d_out, int out_size, void* d_ws, size_t ws_size,
                              hipStream_t stream) {
    const float* in = (const float*)d_in[0];
    float* out = (float*)d_out;
    unsigned long long* keys = (unsigned long long*)d_ws;          // 2048 x u64
    uint32_t* det = (uint32_t*)((char*)d_ws + 2048 * 8);
    uint32_t* fin = (uint32_t*)((char*)d_ws + 2048 * 8 + NB * IMG_WORDS * 4);

    k_det   <<<2048,  256, 0, stream>>>(in, det, keys);
    k_grow  <<<NB,   1024, 0, stream>>>(det, keys, fin);
    k_expand<<<16384, 256, 0, stream>>>(fin, out);
}

// Round 6
// 106.399 us; speedup vs baseline: 2.7147x; 1.0425x over previous
//
#include <hip/hip_runtime.h>
#include <stdint.h>

#define HH 512
#define WW 512
#define NB 8
#define RAD 10
#define NPASS 51
#define WPR 16                 // u32 words per row
#define IMG_WORDS (HH*WPR)     // 8192 words per image
#define STRIDE 540             // words per LDS column: 12 low guard + 512 + 16 high guard
#define GLO 12                 // low guard rows (keeps b128 writes 16B-aligned)
#define RPT 16                 // rows per thread

// ---- Kernel 1: det bits (x1>x0) + per-BLOCK argmax key (no atomics) --------
__global__ __launch_bounds__(256) void k_det(const float* __restrict__ in,
                                             uint32_t* __restrict__ det,
                                             unsigned long long* __restrict__ keys) {
    __shared__ unsigned long long red[4];
    int tid  = blockIdx.x * 256 + threadIdx.x;
    int lane = threadIdx.x & 63;
    int wv   = threadIdx.x >> 6;
    int wave = tid >> 6;
    long long base = (long long)wave * 256;     // 4 rounds x 64 pixels
    unsigned long long best = 0;
    const float2* in2 = (const float2*)in;
    #pragma unroll
    for (int j = 0; j < 4; ++j) {
        long long p = base + j * 64 + lane;
        float2 v = in2[p];
        // round(softmax_1(v)) == 1  <=>  v.y > v.x   (exact; no expf needed)
        float d = v.y - v.x;
        int pred = (d > 0.0f);
        unsigned long long bits = __ballot(pred);
        if (lane == 0) ((unsigned long long*)det)[wave * 4 + j] = bits;
        // argmax of softmax_1 == argmax of d (sigmoid strictly monotone).
        uint32_t du = __float_as_uint(d);
        uint32_t mono = (du & 0x80000000u) ? ~du : (du | 0x80000000u);
        uint32_t pix = (uint32_t)(p & (HH * WW - 1));
        unsigned long long key = ((unsigned long long)mono << 32)
                               | (unsigned long long)(0xFFFFFFFFu - pix);
        best = key > best ? key : best;
    }
    #pragma unroll
    for (int s = 32; s > 0; s >>= 1) {
        unsigned long long o = __shfl_xor(best, s);
        best = o > best ? o : best;
    }
    if (lane == 0) red[wv] = best;
    __syncthreads();
    if (threadIdx.x == 0) {
        unsigned long long b0 = red[0], b1 = red[1], b2 = red[2], b3 = red[3];
        b0 = b0 > b1 ? b0 : b1;
        b2 = b2 > b3 ? b2 : b3;
        keys[blockIdx.x] = b0 > b2 ? b0 : b2;   // plain store, no atomics
    }
}

// ---- Kernel 2: geodesic dilation, 512 thr x 16 rows, 1 barrier/iter --------
__global__ __launch_bounds__(512) void k_grow(const uint32_t* __restrict__ det,
                                              const unsigned long long* __restrict__ keys,
                                              uint32_t* __restrict__ outmask) {
    __shared__ __align__(16) uint32_t hb[2][WPR * STRIDE];  // 69 KB, col-major
    __shared__ uint32_t flag[NPASS];
    __shared__ unsigned long long redk[4];
    int b    = blockIdx.x;
    int t    = threadIdx.x;
    int lane = t & 63;
    int wvid = t >> 6;
    int w    = t & 15;                   // word-in-row == lane&15 (DPP row!)
    int r0   = (t >> 4) << 4;            // first of 16 rows this thread owns
    uint32_t dreg[RPT];
    const uint32_t* db = det + b * IMG_WORDS;
    #pragma unroll
    for (int k = 0; k < RPT; ++k) dreg[k] = db[(r0 + k) * WPR + w];

    // reduce this image's 256 block keys -> single argmax key
    unsigned long long kk = (t < 256) ? keys[b * 256 + t] : 0ull;
    #pragma unroll
    for (int s = 32; s > 0; s >>= 1) {
        unsigned long long o = __shfl_xor(kk, s);
        kk = o > kk ? o : kk;
    }
    if (lane == 0 && wvid < 4) redk[wvid] = kk;

    // zero-init both hb buffers (guards must stay zero) + flags
    for (int i = t; i < 2 * WPR * STRIDE; i += 512) ((uint32_t*)hb)[i] = 0;
    if (t < NPASS) flag[t] = 0;
    __syncthreads();

    unsigned long long key = redk[0];
    key = redk[1] > key ? redk[1] : key;
    key = redk[2] > key ? redk[2] : key;
    key = redk[3] > key ? redk[3] : key;
    uint32_t pix = 0xFFFFFFFFu - (uint32_t)key;
    int sr = pix >> 9, sc = pix & 511;
    uint32_t curreg[RPT];
    #pragma unroll
    for (int k = 0; k < RPT; ++k)        // sparse seed, registers only
        curreg[k] = (sr == r0 + k && (sc >> 5) == w) ? (1u << (sc & 31)) : 0u;

    for (int it = 0; it < NPASS; ++it) {
        uint32_t* colv = &hb[it & 1][w * STRIDE];
        // ---- horizontal dilation radius 10: DPP neighbors + u64 log-doubling
        uint32_t Dv[RPT];
        #pragma unroll
        for (int k = 0; k < RPT; ++k) {
            uint32_t bb = curreg[k];
            uint32_t a = (uint32_t)__builtin_amdgcn_update_dpp(
                0, (int)bb, 0x111, 0xF, 0xF, true);   // word w-1 (0 at w==0)
            uint32_t c = (uint32_t)__builtin_amdgcn_update_dpp(
                0, (int)bb, 0x101, 0xF, 0xF, true);   // word w+1 (0 at w==15)
            unsigned long long W = (unsigned long long)(a >> 22)
                                 | ((unsigned long long)bb << 10)
                                 | ((unsigned long long)c << 42);
            unsigned long long D = W | (W >> 1);      // offsets [0,1]
            D |= D >> 2;                              // [0,3]
            D |= D >> 4;                              // [0,7]
            unsigned long long D7 = D;
            D |= D >> 8;                              // [0,15]
            D |= D7 >> 13;                            // | [13,20] = [0,20]
            Dv[k] = (uint32_t)D;
        }
        // store 16 contiguous rows of column w: 4x ds_write_b128
        *(uint4*)&colv[r0 + GLO]      = make_uint4(Dv[0],  Dv[1],  Dv[2],  Dv[3]);
        *(uint4*)&colv[r0 + GLO + 4]  = make_uint4(Dv[4],  Dv[5],  Dv[6],  Dv[7]);
        *(uint4*)&colv[r0 + GLO + 8]  = make_uint4(Dv[8],  Dv[9],  Dv[10], Dv[11]);
        *(uint4*)&colv[r0 + GLO + 12] = make_uint4(Dv[12], Dv[13], Dv[14], Dv[15]);
        __syncthreads();                 // the ONLY barrier per iteration

        // early exit: fixed point detected at iter it-1 -> curreg already final
        if (it > 0 && flag[it - 1] == 0) break;

        // ---- vertical 21-row OR over 36-row window: wide halo reads --------
        uint32_t x[36];                  // x[j] = H-out of row (r0-10+j)
        {
            uint2 a0 = *(const uint2*)&colv[r0 + 2];      // rows r0-10,r0-9
            uint4 a1 = *(const uint4*)&colv[r0 + 4];      // rows r0-8..r0-5
            uint4 a2 = *(const uint4*)&colv[r0 + 8];      // rows r0-4..r0-1
            uint4 b0 = *(const uint4*)&colv[r0 + 28];     // rows r0+16..r0+19
            uint4 b1 = *(const uint4*)&colv[r0 + 32];     // rows r0+20..r0+23
            uint2 b2 = *(const uint2*)&colv[r0 + 36];     // rows r0+24,r0+25
            x[0] = a0.x;  x[1] = a0.y;
            x[2] = a1.x;  x[3] = a1.y;  x[4] = a1.z;  x[5] = a1.w;
            x[6] = a2.x;  x[7] = a2.y;  x[8] = a2.z;  x[9] = a2.w;
            #pragma unroll
            for (int k = 0; k < RPT; ++k) x[10 + k] = Dv[k];
            x[26] = b0.x; x[27] = b0.y; x[28] = b0.z; x[29] = b0.w;
            x[30] = b1.x; x[31] = b1.y; x[32] = b1.z; x[33] = b1.w;
            x[34] = b2.x; x[35] = b2.y;
        }
        uint32_t s[21];
        s[20] = x[20];
        #pragma unroll
        for (int i = 19; i >= 0; --i) s[i] = x[i] | s[i + 1];
        uint32_t p[36];
        p[21] = x[21];
        #pragma unroll
        for (int i = 22; i < 36; ++i) p[i] = x[i] | p[i - 1];
        uint32_t diff = 0;
        {
            uint32_t nv = dreg[0] & s[0];
            diff |= nv ^ curreg[0];
            curreg[0] = nv;
        }
        #pragma unroll
        for (int k = 1; k < RPT; ++k) {
            uint32_t nv = dreg[k] & (s[k] | p[k + 20]);
            diff |= nv ^ curreg[k];
            curreg[k] = nv;
        }
        if (diff) flag[it] = 1;          // read only after NEXT barrier
    }
    #pragma unroll
    for (int k = 0; k < RPT; ++k)
        outmask[b * IMG_WORDS + (r0 + k) * WPR + w] = curreg[k];
}

// ---- Kernel 3: bits -> float, tiled 8x -------------------------------------
__global__ __launch_bounds__(256) void k_expand(const uint32_t* __restrict__ mask,
                                                float* __restrict__ out) {
    int t   = blockIdx.x * 256 + threadIdx.x;   // 4,194,304 threads, float4 each
    int img = t >> 16;                          // 65536 float4 per image
    int pix = (t & 65535) << 2;
    uint32_t wv = mask[(img & 7) * IMG_WORDS + (pix >> 5)];
    int sh = pix & 31;
    float4 o;
    o.x = (wv >> (sh + 0)) & 1 ? 1.0f : 0.0f;
    o.y = (wv >> (sh + 1)) & 1 ? 1.0f : 0.0f;
    o.z = (wv >> (sh + 2)) & 1 ? 1.0f : 0.0f;
    o.w = (wv >> (sh + 3)) & 1 ? 1.0f : 0.0f;
    ((float4*)out)[t] = o;
}

extern "C" void kernel_launch(void* const* d_in, const int* in_sizes, int n_in,
                              void* d_out, int out_size, void* d_ws, size_t ws_size,
                              hipStream_t stream) {
    const float* in = (const float*)d_in[0];
    float* out = (float*)d_out;
    unsigned long long* keys = (unsigned long long*)d_ws;          // 2048 x u64
    uint32_t* det = (uint32_t*)((char*)d_ws + 2048 * 8);
    uint32_t* fin = (uint32_t*)((char*)d_ws + 2048 * 8 + NB * IMG_WORDS * 4);

    k_det   <<<2048,  256, 0, stream>>>(in, det, keys);
    k_grow  <<<NB,    512, 0, stream>>>(det, keys, fin);
    k_expand<<<16384, 256, 0, stream>>>(fin, out);
}